// Round 10
// baseline (689.707 us; speedup 1.0000x reference)
//
#include <hip/hip_runtime.h>

#define N_PIX 16384   // 128*128
#define CC    192
#define C3    576
#define KK    192     // GEMM K (=CC)
#define HD    24
#define GSPLIT 32     // gram K-split

typedef __attribute__((ext_vector_type(8))) short short8;   // 8 bf16 = 4 VGPR
typedef __attribute__((ext_vector_type(4))) float f32x4;    // MFMA acc

__device__ __forceinline__ unsigned short f2bf(float x) {
    unsigned u = __float_as_uint(x);
    u += 0x7fff + ((u >> 16) & 1);          // round-to-nearest-even
    return (unsigned short)(u >> 16);
}
__device__ __forceinline__ float bf2f(unsigned short s) {
    return __uint_as_float(((unsigned)s) << 16);
}
__device__ __forceinline__ int pack2(unsigned short lo, unsigned short hi) {
    return (int)(((unsigned)hi << 16) | (unsigned)lo);
}

// async global->LDS, 16B per lane; lds dest is wave-uniform base + lane*16
__device__ __forceinline__ void g2l16(const unsigned short* g, unsigned short* l) {
    __builtin_amdgcn_global_load_lds(
        (const __attribute__((address_space(1))) void*)g,
        (__attribute__((address_space(3))) void*)l, 16, 0, 0);
}

// K0: fp32 -> bf16 bulk convert (vector of 4) — weights only
__global__ __launch_bounds__(256) void cvt_f32_bf16(const float* __restrict__ src,
                                                    unsigned short* __restrict__ dst, int n4) {
    int i = blockIdx.x * 256 + threadIdx.x;
    if (i < n4) {
        float4 v = ((const float4*)src)[i];
        ushort4 o;
        o.x = f2bf(v.x); o.y = f2bf(v.y); o.z = f2bf(v.z); o.w = f2bf(v.w);
        ((ushort4*)dst)[i] = o;
    }
}

// ---------------------------------------------------------------------------
// qkv v7: Y[z][576,16384] = w_bf[576,192] @ x[z][192,16384]  (fp32 B)
// v6 structure + counted-vmcnt pipeline (T3/T4) + writeB-after-MFMA (T14)
// + bijective XCD-chunked block swizzle (T1, nwg=6144 % 8 == 0).
// Hand-unrolled 3 K-steps; raw s_barrier; vmcnt(11) = 8 B-loads + 3 A-g2l16
// intentionally left in flight across the barrier; only the last iteration
// drains vmcnt fully.
// ---------------------------------------------------------------------------
__global__ __launch_bounds__(512, 4) void qkv_mfma(const unsigned short* __restrict__ wbf,
                                                   const float* __restrict__ rgb,
                                                   const float* __restrict__ ir,
                                                   unsigned short* __restrict__ Ybf) {
    // XCD-chunked swizzle: consecutive logical blocks (3 m-groups sharing a
    // B-slice, then consecutive n) stay on ONE XCD's L2.
    const int id  = blockIdx.x;            // 0..6143
    const int nid = (id & 7) * 768 + (id >> 3);
    const int m0  = (nid % 3) * 192;
    const int r   = nid / 3;               // 0..2047
    const int n0  = (r & 127) * 128;
    const int z   = r >> 7;

    const float* xg = ((z >= 8) ? ir : rgb) + (long)(z & 7) * CC * N_PIX;
    unsigned short* y = Ybf + (long)z * C3 * N_PIX;

    __shared__ unsigned short As[2][192 * 64];
    __shared__ unsigned short Bs[2][128 * 64];

    const int tid  = threadIdx.x;
    const int wave = tid >> 6, lane = tid & 63;
    const int quad = lane >> 4, l15 = lane & 15;
    const int wr = wave >> 2, wc = wave & 3;   // 2 x 4 wave grid

    f32x4 acc[6][2];
#pragma unroll
    for (int i = 0; i < 6; i++)
#pragma unroll
        for (int j = 0; j < 2; j++) acc[i][j] = (f32x4)0.f;

    // B staging: nq = col-pair (wave-contiguous -> coalesced), kq = k-chunk of 8
    const int nq = tid & 63, kq = tid >> 6;

    float2 bv[8];
    auto loadB = [&](int k0) {                 // issue 8 global fp32x2 loads
#pragma unroll
        for (int j = 0; j < 8; j++)
            bv[j] = *(const float2*)(xg + (long)(k0 + kq * 8 + j) * N_PIX + n0 + nq * 2);
    };
    auto stageA = [&](int buf, int k0) {       // issue 3 g2l16 per wave
#pragma unroll
        for (int s = 0; s < 3; s++) {
            int j = s * 8 + wave;
            int q = j * 64 + lane;
            int m = q >> 3, c = (q & 7) ^ (m & 7);
            g2l16(wbf + (long)(m0 + m) * KK + k0 + c * 8, &As[buf][j * 512]);
        }
    };
    auto writeB = [&](int buf) {               // waits vmcnt(3) (its bv only)
#pragma unroll
        for (int i = 0; i < 2; i++) {
            int n = nq * 2 + i;
            unsigned short us[8];
#pragma unroll
            for (int j = 0; j < 8; j++) us[j] = f2bf(i ? bv[j].y : bv[j].x);
            int4 pk = make_int4(pack2(us[0], us[1]), pack2(us[2], us[3]),
                                pack2(us[4], us[5]), pack2(us[6], us[7]));
            int c = kq ^ (n & 7);
            *(int4*)&Bs[buf][n * 64 + c * 8] = pk;
        }
    };
    auto mfma_step = [&](int buf) {
        const unsigned short* A  = As[buf];
        const unsigned short* Bl = Bs[buf];
#pragma unroll
        for (int kk = 0; kk < 2; kk++) {
            short8 a[6], b[2];
#pragma unroll
            for (int mi = 0; mi < 6; mi++) {
                int rr = wr * 96 + mi * 16 + l15;
                int c = (kk * 4 + quad) ^ (rr & 7);
                a[mi] = *(const short8*)&A[rr * 64 + c * 8];
            }
#pragma unroll
            for (int ni = 0; ni < 2; ni++) {
                int n = wc * 32 + ni * 16 + l15;
                int c = (kk * 4 + quad) ^ (n & 7);
                b[ni] = *(const short8*)&Bl[n * 64 + c * 8];
            }
#pragma unroll
            for (int mi = 0; mi < 6; mi++)
#pragma unroll
                for (int ni = 0; ni < 2; ni++)
                    acc[mi][ni] = __builtin_amdgcn_mfma_f32_16x16x32_bf16(a[mi], b[ni], acc[mi][ni], 0, 0, 0);
        }
    };

    // ---- prologue: tile 0 ----
    loadB(0);
    stageA(0, 0);
    writeB(0);                                   // vmcnt(3): A(buf0) stays in flight

    // ---- it 0 ----
    loadB(64);
    stageA(1, 64);
    asm volatile("s_waitcnt vmcnt(11) lgkmcnt(0)" ::: "memory");  // drain A(buf0) only
    __builtin_amdgcn_s_barrier();
    __builtin_amdgcn_sched_barrier(0);
    mfma_step(0);
    writeB(1);                                   // vmcnt(3): B(64) done, A(buf1) in flight
    asm volatile("s_waitcnt lgkmcnt(0)" ::: "memory");
    __builtin_amdgcn_s_barrier();

    // ---- it 1 ----
    loadB(128);
    stageA(0, 128);
    asm volatile("s_waitcnt vmcnt(11) lgkmcnt(0)" ::: "memory");  // drain A(buf1) only
    __builtin_amdgcn_s_barrier();
    __builtin_amdgcn_sched_barrier(0);
    mfma_step(1);
    writeB(0);
    asm volatile("s_waitcnt lgkmcnt(0)" ::: "memory");
    __builtin_amdgcn_s_barrier();

    // ---- it 2 (last) ----
    asm volatile("s_waitcnt vmcnt(0) lgkmcnt(0)" ::: "memory");   // drain A(buf0)
    __builtin_amdgcn_s_barrier();
    __builtin_amdgcn_sched_barrier(0);
    mfma_step(0);

    // ---- epilogue: C/D layout col=lane&15, row=quad*4+reg ----
#pragma unroll
    for (int mi = 0; mi < 6; mi++)
#pragma unroll
        for (int ni = 0; ni < 2; ni++)
#pragma unroll
            for (int rr = 0; rr < 4; rr++) {
                int row = m0 + wr * 96 + mi * 16 + quad * 4 + rr;
                int col = n0 + wc * 32 + ni * 16 + l15;
                y[(long)row * N_PIX + col] = f2bf(acc[mi][ni][rr]);
            }
}

// ---------------------------------------------------------------------------
// gram v3 (MFMA): per (which,b): G[192,192] = Q[192,N] @ K[192,N]^T, K-split 32.
// 512 thr = 8 waves (4x2), wave tile 48x96, acc[3][6]. K-step 64, 8 iters.
// Only the 8 per-head 24x24 diagonal blocks are stored (compacted).
// ---------------------------------------------------------------------------
__global__ __launch_bounds__(512, 2) void gram_mfma(const unsigned short* __restrict__ Zbf,
                                                    float* __restrict__ gpart) {
    const int ks = blockIdx.x;          // 0..31
    const int zp = blockIdx.y;          // which*8 + b
    const int which = zp >> 3, b = zp & 7;
    const int zq = which ? 8 + b : b;
    const int zk = which ? b : 8 + b;
    const unsigned short* Qg = Zbf + (long)zq * C3 * N_PIX;          // q chans 0..191
    const unsigned short* Kg = Zbf + ((long)zk * C3 + CC) * N_PIX;   // k chans 0..191

    __shared__ unsigned short Qs[2][192 * 64];
    __shared__ unsigned short Ks[2][192 * 64];

    const int tid  = threadIdx.x;
    const int wave = tid >> 6, lane = tid & 63;
    const int quad = lane >> 4, l15 = lane & 15;
    const int wr = wave >> 1, wc = wave & 1;   // 4 x 2 wave grid

    f32x4 acc[3][6];
#pragma unroll
    for (int i = 0; i < 3; i++)
#pragma unroll
        for (int j = 0; j < 6; j++) acc[i][j] = (f32x4)0.f;

    const int base = ks * 512;

    auto stage = [&](int buf, int k0) {
#pragma unroll
        for (int s = 0; s < 3; s++) {
            int j = s * 8 + wave;
            int q = j * 64 + lane;
            int m = q >> 3, c = (q & 7) ^ (m & 7);
            g2l16(Qg + (long)m * N_PIX + k0 + c * 8, &Qs[buf][j * 512]);
            g2l16(Kg + (long)m * N_PIX + k0 + c * 8, &Ks[buf][j * 512]);
        }
    };

    stage(0, base);
    __syncthreads();
    int cur = 0;
    for (int it = 0; it < 8; ++it) {
        if (it < 7) stage(cur ^ 1, base + (it + 1) * 64);
        const unsigned short* Q = Qs[cur];
        const unsigned short* Kl = Ks[cur];
#pragma unroll
        for (int kk = 0; kk < 2; kk++) {
            short8 a[3], bf[6];
#pragma unroll
            for (int mi = 0; mi < 3; mi++) {
                int r = wr * 48 + mi * 16 + l15;
                int c = (kk * 4 + quad) ^ (r & 7);
                a[mi] = *(const short8*)&Q[r * 64 + c * 8];
            }
#pragma unroll
            for (int ni = 0; ni < 6; ni++) {
                int n = wc * 96 + ni * 16 + l15;
                int c = (kk * 4 + quad) ^ (n & 7);
                bf[ni] = *(const short8*)&Kl[n * 64 + c * 8];
            }
#pragma unroll
            for (int mi = 0; mi < 3; mi++)
#pragma unroll
                for (int ni = 0; ni < 6; ni++)
                    acc[mi][ni] = __builtin_amdgcn_mfma_f32_16x16x32_bf16(a[mi], bf[ni], acc[mi][ni], 0, 0, 0);
        }
        __syncthreads();
        cur ^= 1;
    }

    // store only diag 24x24 head blocks, compacted: [zp][ks][head][24][24]
#pragma unroll
    for (int mi = 0; mi < 3; mi++)
#pragma unroll
        for (int ni = 0; ni < 6; ni++)
#pragma unroll
            for (int r = 0; r < 4; r++) {
                int row = wr * 48 + mi * 16 + quad * 4 + r;
                int col = wc * 96 + ni * 16 + l15;
                int hr = row / 24, hc = col / 24;
                if (hr == hc)
                    gpart[(((long)zp * GSPLIT + ks) * 8 + hr) * 576 +
                          (row - hr * 24) * 24 + (col - hc * 24)] = acc[mi][ni][r];
            }
}

// ---------------------------------------------------------------------------
// old GEMM body — used by out_mfma.
// ---------------------------------------------------------------------------
__device__ __forceinline__ void mfma_gemm_old(const unsigned short* __restrict__ Abf,
                                              const unsigned short* __restrict__ Bsrc,
                                              float* __restrict__ Cdst,
                                              int m0, int n0) {
    __shared__ unsigned short As[192][44];
    __shared__ unsigned short Bs[128][44];

    const int tid  = threadIdx.x;
    const int wave = tid >> 6, lane = tid & 63;
    const int quad = lane >> 4, l15 = lane & 15;
    const int wr = wave >> 2, wc = wave & 3;

    f32x4 acc[6][2];
#pragma unroll
    for (int i = 0; i < 6; i++)
#pragma unroll
        for (int j = 0; j < 2; j++) acc[i][j] = (f32x4)0.f;

    const int kg = tid & 7;
    const int n2 = tid >> 3;

    for (int k0 = 0; k0 < KK; k0 += 32) {
        {
            int row = tid >> 2, kc = (tid & 3) * 8;
            *(int4*)&As[row][kc] = *(const int4*)(Abf + (long)(m0 + row) * KK + k0 + kc);
            if (tid < 256) {
                int ch = tid + 512;
                int row2 = ch >> 2, kc2 = (ch & 3) * 8;
                *(int4*)&As[row2][kc2] = *(const int4*)(Abf + (long)(m0 + row2) * KK + k0 + kc2);
            }
        }
        {
            ushort2 v[4];
#pragma unroll
            for (int j = 0; j < 4; j++)
                v[j] = *(const ushort2*)(Bsrc + (long)(k0 + kg * 4 + j) * N_PIX + n0 + n2 * 2);
#pragma unroll
            for (int i = 0; i < 2; i++) {
                unsigned short us[4];
#pragma unroll
                for (int j = 0; j < 4; j++) us[j] = i ? v[j].y : v[j].x;
                int2 pk = make_int2(pack2(us[0], us[1]), pack2(us[2], us[3]));
                *(int2*)&Bs[n2 * 2 + i][kg * 4] = pk;
            }
        }
        __syncthreads();

        short8 a[6], b[2];
#pragma unroll
        for (int mi = 0; mi < 6; mi++)
            a[mi] = *(const short8*)&As[wr * 96 + mi * 16 + l15][quad * 8];
#pragma unroll
        for (int ni = 0; ni < 2; ni++)
            b[ni] = *(const short8*)&Bs[wc * 32 + ni * 16 + l15][quad * 8];
#pragma unroll
        for (int mi = 0; mi < 6; mi++)
#pragma unroll
            for (int ni = 0; ni < 2; ni++)
                acc[mi][ni] = __builtin_amdgcn_mfma_f32_16x16x32_bf16(a[mi], b[ni], acc[mi][ni], 0, 0, 0);
        __syncthreads();
    }

#pragma unroll
    for (int mi = 0; mi < 6; mi++)
#pragma unroll
        for (int ni = 0; ni < 2; ni++)
#pragma unroll
            for (int r = 0; r < 4; r++) {
                int row = m0 + wr * 96 + mi * 16 + quad * 4 + r;
                int col = n0 + wc * 32 + ni * 16 + l15;
                Cdst[(long)row * N_PIX + col] = acc[mi][ni][r];
            }
}

// K5: out[z][192,N] = weff_bf[z][192,192] @ V[z][192,N], fp32 out
__global__ __launch_bounds__(512, 4) void out_mfma(const unsigned short* __restrict__ weff,
                                                   const unsigned short* __restrict__ Zbf,
                                                   float* __restrict__ out) {
    const int z = blockIdx.z;
    const unsigned short* V = Zbf + ((long)z * C3 + 2 * CC) * N_PIX;
    float* C = out + (long)z * CC * N_PIX;
    mfma_gemm_old(weff + (long)z * CC * CC, V, C, 0, blockIdx.x * 128);
}

// K2: depthwise 3x3 SAME, bf16 in/out, 8 px/thread + per-block norm partials
// (no atomics: nrm[z][oc][blk] summed later in gram_reduce_softmax).
__global__ __launch_bounds__(256) void dwconv3x3(const unsigned short* __restrict__ Ybf,
                                                 const float* __restrict__ wdw,
                                                 unsigned short* __restrict__ Zbf,
                                                 float* __restrict__ nrm) {
    const int z  = blockIdx.z;
    const int oc = blockIdx.y;
    const int idx = blockIdx.x * 256 + threadIdx.x;   // 0..2047
    const int p0  = idx * 8;
    const int h   = p0 >> 7;
    const int w0  = p0 & 127;
    const int wq  = threadIdx.x & 15;
    const unsigned short* Yc = Ybf + ((long)z * C3 + oc) * N_PIX;

    float wk[9];
#pragma unroll
    for (int i = 0; i < 9; i++) wk[i] = wdw[oc * 9 + i];

    float f[3][8];
#pragma unroll
    for (int ry = 0; ry < 3; ry++) {
        const int hy = h + ry - 1;
        int4 raw = make_int4(0, 0, 0, 0);
        if (hy >= 0 && hy <= 127)
            raw = *(const int4*)(Yc + hy * 128 + w0);
        f[ry][0] = bf2f((unsigned short)(raw.x & 0xffff));
        f[ry][1] = bf2f((unsigned short)((unsigned)raw.x >> 16));
        f[ry][2] = bf2f((unsigned short)(raw.y & 0xffff));
        f[ry][3] = bf2f((unsigned short)((unsigned)raw.y >> 16));
        f[ry][4] = bf2f((unsigned short)(raw.z & 0xffff));
        f[ry][5] = bf2f((unsigned short)((unsigned)raw.z >> 16));
        f[ry][6] = bf2f((unsigned short)(raw.w & 0xffff));
        f[ry][7] = bf2f((unsigned short)((unsigned)raw.w >> 16));
    }

    float acc[8];
#pragma unroll
    for (int j = 0; j < 8; j++) acc[j] = 0.f;

#pragma unroll
    for (int ry = 0; ry < 3; ry++) {
        float l = __shfl_up(f[ry][7], 1);
        float r = __shfl_down(f[ry][0], 1);
        if (wq == 0)  l = 0.f;
        if (wq == 15) r = 0.f;
        const float wl = wk[ry * 3 + 0], wc = wk[ry * 3 + 1], wr = wk[ry * 3 + 2];
        acc[0] = fmaf(wl, l, acc[0]);
#pragma unroll
        for (int j = 1; j < 8; j++) acc[j] = fmaf(wl, f[ry][j - 1], acc[j]);
#pragma unroll
        for (int j = 0; j < 8; j++) acc[j] = fmaf(wc, f[ry][j], acc[j]);
#pragma unroll
        for (int j = 0; j < 7; j++) acc[j] = fmaf(wr, f[ry][j + 1], acc[j]);
        acc[7] = fmaf(wr, r, acc[7]);
    }

    ushort4 o[2];
    unsigned short* po = (unsigned short*)o;
#pragma unroll
    for (int j = 0; j < 8; j++) po[j] = f2bf(acc[j]);
    *(int4*)(Zbf + ((long)z * C3 + oc) * N_PIX + p0) = *(const int4*)o;

    // block-level sum of squares of the bf16-rounded values (q/k channels only)
    __shared__ float red[4];
    float ss = 0.f;
#pragma unroll
    for (int j = 0; j < 8; j++) {
        float v = bf2f(po[j]);
        ss = fmaf(v, v, ss);
    }
#pragma unroll
    for (int off = 32; off > 0; off >>= 1)
        ss += __shfl_down(ss, off);
    if ((threadIdx.x & 63) == 0) red[threadIdx.x >> 6] = ss;
    __syncthreads();
    if (threadIdx.x == 0 && oc < 2 * CC)
        nrm[((long)z * (2 * CC) + oc) * 8 + blockIdx.x] = red[0] + red[1] + red[2] + red[3];
}

// K3b: reduce gram splits + norm partials, normalize, temperature, softmax -> P
__global__ __launch_bounds__(256) void gram_reduce_softmax(const float* __restrict__ gpart,
                                                           const float* __restrict__ nrm,
                                                           const float* __restrict__ temperature,
                                                           float* __restrict__ P) {
    const int g = blockIdx.x;           // which*64 + b*8 + head
    const int which = g >> 6, b = (g >> 3) & 7, head = g & 7;
    const int zp = which * 8 + b;
    const int zq = which ? 8 + b : b;
    const int zk = which ? b : 8 + b;
    __shared__ float Gs[576];
    __shared__ float invq[24], invk[24];

    const int t = threadIdx.x;
    for (int e = t; e < 576; e += 256) {
        float s = 0.f;
        for (int sp = 0; sp < GSPLIT; sp++)
            s += gpart[(((long)zp * GSPLIT + sp) * 8 + head) * 576 + e];
        Gs[e] = s;
    }
    if (t < 24) {
        float s = 0.f;
#pragma unroll
        for (int b8 = 0; b8 < 8; b8++)
            s += nrm[((long)zq * (2 * CC) + head * HD + t) * 8 + b8];
        invq[t] = 1.f / fmaxf(sqrtf(s), 1e-12f);
    } else if (t >= 32 && t < 56) {
        float s = 0.f;
#pragma unroll
        for (int b8 = 0; b8 < 8; b8++)
            s += nrm[((long)zk * (2 * CC) + CC + head * HD + (t - 32)) * 8 + b8];
        invk[t - 32] = 1.f / fmaxf(sqrtf(s), 1e-12f);
    }
    __syncthreads();
    if (t < 24) {
        const float temp = temperature[head];
        float row[24];
        float m = -1e30f;
#pragma unroll
        for (int d = 0; d < 24; d++) {
            row[d] = Gs[t * 24 + d] * invq[t] * invk[d] * temp;
            m = fmaxf(m, row[d]);
        }
        float ssum = 0.f;
#pragma unroll
        for (int d = 0; d < 24; d++) {
            row[d] = expf(row[d] - m);
            ssum += row[d];
        }
        const float inv = 1.f / ssum;
#pragma unroll
        for (int d = 0; d < 24; d++)
            P[(long)g * 576 + t * 24 + d] = row[d] * inv;
    }
}

// K4: weff_bf[o][b] = wproj @ blockdiag(P[1-o][b])  (bf16 out)
__global__ __launch_bounds__(256) void build_weff(const float* __restrict__ wproj,
                                                  const float* __restrict__ P,
                                                  unsigned short* __restrict__ weff) {
    const int o = blockIdx.z, b = blockIdx.y;
    const int e = blockIdx.x * 256 + threadIdx.x;   // 0..36863
    const int co = e / 192, col = e % 192;
    const int head = col / 24, d = col % 24;
    const int which = 1 - o;
    const float* Pp = P + (long)(which * 64 + b * 8 + head) * 576;
    const float* wp = wproj + co * 192 + head * 24;
    float acc = 0.f;
#pragma unroll
    for (int hc = 0; hc < 24; hc++)
        acc = fmaf(wp[hc], Pp[hc * 24 + d], acc);
    weff[((long)(o * 8 + b) * 192 + co) * 192 + col] = f2bf(acc);
}

extern "C" void kernel_launch(void* const* d_in, const int* in_sizes, int n_in,
                              void* d_out, int out_size, void* d_ws, size_t ws_size,
                              hipStream_t stream) {
    (void)in_sizes; (void)n_in; (void)out_size; (void)ws_size;
    const float* rgb    = (const float*)d_in[0];
    const float* ir     = (const float*)d_in[1];
    const float* w_qkv  = (const float*)d_in[2];
    const float* w_dw   = (const float*)d_in[3];
    const float* w_proj = (const float*)d_in[4];
    const float* temp   = (const float*)d_in[5];
    float* out = (float*)d_out;

    char* wsb = (char*)d_ws;
    unsigned short* Y_bf    = (unsigned short*)(wsb);                 // 301,989,888 B
    unsigned short* Z_bf    = (unsigned short*)(wsb + 301989888L);    // 301,989,888 B
    float*          gpart   = (float*)(wsb);                          // alias Y: dead after dwconv (9.44 MB)
    unsigned short* w_bf    = (unsigned short*)(wsb + 603979776L);    //     221,184 B
    unsigned short* weff_bf = (unsigned short*)(wsb + 604200960L);    //   1,179,648 B
    float*          nrm     = (float*)(wsb + 605380608L);             //     196,608 B
    float*          P       = (float*)(wsb + 607936512L);             //     294,912 B

    cvt_f32_bf16<<<108, 256, 0, stream>>>(w_qkv, w_bf, 27648);
    qkv_mfma<<<6144, 512, 0, stream>>>(w_bf, rgb, ir, Y_bf);
    dwconv3x3<<<dim3(8, 576, 16), 256, 0, stream>>>(Y_bf, w_dw, Z_bf, nrm);
    gram_mfma<<<dim3(GSPLIT, 16), 512, 0, stream>>>(Z_bf, gpart);
    gram_reduce_softmax<<<128, 256, 0, stream>>>(gpart, nrm, temp, P);
    build_weff<<<dim3(144, 8, 2), 256, 0, stream>>>(w_proj, P, weff_bf);
    out_mfma<<<dim3(128, 1, 16), 512, 0, stream>>>(weff_bf, Z_bf, out);
}